// Round 8
// baseline (295.896 us; speedup 1.0000x reference)
//
#include <hip/hip_runtime.h>
#include <hip/hip_bf16.h>

typedef __bf16 bf16x8 __attribute__((ext_vector_type(8)));
typedef unsigned short u16x8 __attribute__((ext_vector_type(8)));
typedef float f32x4 __attribute__((ext_vector_type(4)));

using gptr_t = const __attribute__((address_space(1))) unsigned int*;
using lptr_t = __attribute__((address_space(3))) unsigned int*;
#define gp(x) ((gptr_t)(const void*)(x))
#define lp(x) ((lptr_t)(void*)(x))

// counted wait + sched fence (rule #18)
#define VMW(N)                                            \
  do {                                                    \
    asm volatile("s_waitcnt vmcnt(" #N ")" ::: "memory"); \
    __builtin_amdgcn_sched_barrier(0);                    \
  } while (0)
#define MEMFENCE asm volatile("" ::: "memory")

// ---------------------------------------------------------------------------
// Prep: pack W1 [1280x32] and W2 [32x128] (f32, row-major) into bf16 MFMA
// B-fragment order for mfma_f32_16x16x32_bf16.
// (lane l, elem j) <- W[k = kt*32 + (l>>4)*8 + j][n = nt*16 + (l&15)]
// wsB1[((kt*2+nt)*64 + l)*8 + j], wsB2[((nt)*64 + l)*8 + j]
// ---------------------------------------------------------------------------
__global__ __launch_bounds__(256) void prep_w_kernel(
    const float* __restrict__ W1, const float* __restrict__ W2,
    unsigned short* __restrict__ wsB1, unsigned short* __restrict__ wsB2) {
  int tid = blockIdx.x * 256 + threadIdx.x;
  if (tid < 40960) {                      // W1 frags: 40 ktiles * 2 ntiles * 512
    int j = tid & 7, l = (tid >> 3) & 63, nt = (tid >> 9) & 1, kt = tid >> 10;
    int k = kt * 32 + ((l >> 4) << 3) + j;
    int n = nt * 16 + (l & 15);
    __bf16 v = (__bf16)W1[k * 32 + n];
    wsB1[tid] = __builtin_bit_cast(unsigned short, v);
  } else if (tid < 45056) {               // W2 frags: 8 ntiles * 512
    int t = tid - 40960;
    int j = t & 7, l = (t >> 3) & 63, nt = t >> 9;
    int k = ((l >> 4) << 3) + j;
    int n = nt * 16 + (l & 15);
    __bf16 v = (__bf16)W2[k * 128 + n];
    wsB2[t] = __builtin_bit_cast(unsigned short, v);
  }
}

// ---------------------------------------------------------------------------
// Block = 256 threads = 64 edges = 4 strips (one per wave). 20 chunks of
// 16 rows x 256 cols f32 (16 KB): src strips 0..3 (2 chunks each), dst
// likewise, ea strips (1 fully-contiguous chunk each). 3-slot LDS ring;
// counted per-wave vmcnt(8) across RAW s_barriers (T3+T4: the pipe never
// drains to 0 in the loop). Each wave stages 4 rows/chunk (1 KB linear run
// per instr); chunk c is consumed only by its strip-owner wave (8 k-tiles x
// 2 MFMAs). 32B-granule XOR swizzle (key=row&7) applied source+read, LDS
// linear (rule 21). Epilogue per R7: LDS h-transpose + GEMM2.
// ---------------------------------------------------------------------------
template <bool USE_WS>
__global__ __launch_bounds__(256) void edge_mlp_kernel(
    const float* __restrict__ src, const float* __restrict__ dst,
    const float* __restrict__ ea, const float* __restrict__ W1,
    const float* __restrict__ b1, const float* __restrict__ W2,
    const float* __restrict__ b2, const unsigned short* __restrict__ wsB1,
    const unsigned short* __restrict__ wsB2, float* __restrict__ out, int nE) {
  __shared__ alignas(16) float xb[3][16][256];  // 48 KB ring
  const int lane = threadIdx.x & 63;
  const int wave = threadIdx.x >> 6;
  const int l15 = lane & 15;
  const int lh = lane >> 4;

  // m204 bijective XCD swizzle
  const int nwg = gridDim.x;
  const int q = nwg >> 3, rmd = nwg & 7;
  const int xcd = (int)blockIdx.x & 7, idx = (int)blockIdx.x >> 3;
  const int bid =
      (xcd < rmd ? xcd * (q + 1) : rmd * (q + 1) + (xcd - rmd) * q) + idx;

  const long e0 = (long)bid * 64;
  if (e0 >= nE) return;

  const float bias0 = b1[l15];
  const float bias1 = b1[16 + l15];

  f32x4 acc0 = {0.f, 0.f, 0.f, 0.f};
  f32x4 acc1 = {0.f, 0.f, 0.f, 0.f};

  if constexpr (USE_WS) {
    // ---- stage chunk c into ring slot s: this wave issues rows 4w..4w+3 ----
    auto stage = [&](int c, int s) {
#pragma unroll
      for (int i = 0; i < 4; ++i) {
        const int r = wave * 4 + i;  // chunk-local row 0..15
        // XOR-swizzled source within the 1KB run: stored 32B-pair P=lane>>1
        // holds source pair P^(r&7); 16B half passes through.
        const int unit = ((((lane >> 1) ^ (r & 7)) << 1) | (lane & 1));
        const float* p;
        if (c < 8) {
          const int sw = c >> 1, h = c & 1;
          p = src + (e0 + sw * 16 + r) * 512 + h * 256 + unit * 4;
        } else if (c < 16) {
          const int sw = (c - 8) >> 1, h = c & 1;
          p = dst + (e0 + sw * 16 + r) * 512 + h * 256 + unit * 4;
        } else {
          const int sw = c - 16;
          p = ea + (e0 + sw * 16 + r) * 256 + unit * 4;
        }
        __builtin_amdgcn_global_load_lds(gp(p), lp(&xb[s][r][0]), 16, 0, 0);
      }
    };

    // ---- consume chunk c (only strip-owner wave): 8 k-tiles x 2 MFMAs ----
    auto consume = [&](int c, int s) {
      const int tbase = (c < 8) ? (c & 1) * 8
                      : (c < 16) ? 16 + (c & 1) * 8
                                 : 32;
#pragma unroll
      for (int tt = 0; tt < 8; ++tt) {
        const int pp = (tt * 4 + lh) ^ (l15 & 7);  // stored 32B granule
        const f32x4* ap =
            (const f32x4*)((const char*)&xb[s][l15][0] + pp * 32);
        f32x4 lo = ap[0], hi = ap[1];
        bf16x8 a;
        a[0] = (__bf16)lo[0]; a[1] = (__bf16)lo[1];
        a[2] = (__bf16)lo[2]; a[3] = (__bf16)lo[3];
        a[4] = (__bf16)hi[0]; a[5] = (__bf16)hi[1];
        a[6] = (__bf16)hi[2]; a[7] = (__bf16)hi[3];
        const int t = tbase + tt;
        bf16x8 w0 = __builtin_bit_cast(
            bf16x8, *(const u16x8*)(wsB1 + (t * 2 + 0) * 512 + lane * 8));
        bf16x8 w1 = __builtin_bit_cast(
            bf16x8, *(const u16x8*)(wsB1 + (t * 2 + 1) * 512 + lane * 8));
        acc0 = __builtin_amdgcn_mfma_f32_16x16x32_bf16(a, w0, acc0, 0, 0, 0);
        acc1 = __builtin_amdgcn_mfma_f32_16x16x32_bf16(a, w1, acc1, 0, 0, 0);
      }
    };

    stage(0, 0);
    stage(1, 1);
    stage(2, 2);  // 12 loads/wave in flight
#pragma unroll
    for (int c = 0; c < 20; ++c) {
      // certify chunk c complete: outstanding drops to {c+1,c+2} = 8
      if (c <= 17) { VMW(8); } else if (c == 18) { VMW(4); } else { VMW(0); }
      __builtin_amdgcn_s_barrier();   // all waves certified their rows of c
      MEMFENCE;
      const int wc = (c < 8) ? (c >> 1) : (c < 16) ? ((c - 8) >> 1) : (c - 16);
      if (wave == wc) consume(c, c % 3);
      MEMFENCE;
      __builtin_amdgcn_s_barrier();   // consume(c) done before slot reuse
      if (c + 3 < 20) stage(c + 3, (c + 3) % 3);
    }
  } else {
    // correctness fallback (no workspace / nE not multiple of 64)
    long rowf = e0 + wave * 16 + l15;
    if (rowf >= nE) rowf = nE - 1;
    for (int t = 0; t < 40; ++t) {
      const float* p = (t < 16) ? (src + rowf * 512 + t * 32 + lh * 8)
                     : (t < 32) ? (dst + rowf * 512 + (t - 16) * 32 + lh * 8)
                                : (ea + rowf * 256 + (t - 32) * 32 + lh * 8);
      f32x4 lo = *(const f32x4*)p;
      f32x4 hi = *(const f32x4*)(p + 4);
      bf16x8 a, bf0, bf1;
      a[0] = (__bf16)lo[0]; a[1] = (__bf16)lo[1];
      a[2] = (__bf16)lo[2]; a[3] = (__bf16)lo[3];
      a[4] = (__bf16)hi[0]; a[5] = (__bf16)hi[1];
      a[6] = (__bf16)hi[2]; a[7] = (__bf16)hi[3];
#pragma unroll
      for (int j = 0; j < 8; ++j) {
        int k = t * 32 + lh * 8 + j;
        bf0[j] = (__bf16)W1[k * 32 + l15];
        bf1[j] = (__bf16)W1[k * 32 + 16 + l15];
      }
      acc0 = __builtin_amdgcn_mfma_f32_16x16x32_bf16(a, bf0, acc0, 0, 0, 0);
      acc1 = __builtin_amdgcn_mfma_f32_16x16x32_bf16(a, bf1, acc1, 0, 0, 0);
    }
  }

  // ---- bias + ELU; per-wave h-transpose in private 4KB of slot 0
  // (slot 0 last consumed at c=18, barrier'ed; each wave private region).
  unsigned short* hl = ((unsigned short*)&xb[0][0][0]) + wave * 2048;
#pragma unroll
  for (int r = 0; r < 4; ++r) {
    int hrow = lh * 4 + r;  // C/D layout: row=(lane>>4)*4+reg, col=lane&15
    float h0 = acc0[r] + bias0;
    float h1 = acc1[r] + bias1;
    h0 = h0 > 0.f ? h0 : (__expf(h0) - 1.f);
    h1 = h1 > 0.f ? h1 : (__expf(h1) - 1.f);
    __bf16 v0 = (__bf16)h0, v1 = (__bf16)h1;
    hl[hrow * 40 + l15] = __builtin_bit_cast(unsigned short, v0);
    hl[hrow * 40 + 16 + l15] = __builtin_bit_cast(unsigned short, v1);
  }
  asm volatile("s_waitcnt lgkmcnt(0)" ::: "memory");
  __builtin_amdgcn_sched_barrier(0);
  bf16x8 ha =
      __builtin_bit_cast(bf16x8, *(const u16x8*)(hl + l15 * 40 + lh * 8));

  // ---- GEMM2: out tiles over 8 ntiles of 16 cols ----
  f32x4 o[8];
#pragma unroll
  for (int nt = 0; nt < 8; ++nt) {
    bf16x8 bw;
    if (USE_WS) {
      bw = __builtin_bit_cast(bf16x8,
                              *(const u16x8*)(wsB2 + nt * 512 + lane * 8));
    } else {
#pragma unroll
      for (int j = 0; j < 8; ++j)
        bw[j] = (__bf16)W2[(lh * 8 + j) * 128 + nt * 16 + l15];
    }
    f32x4 z = {0.f, 0.f, 0.f, 0.f};
    o[nt] = __builtin_amdgcn_mfma_f32_16x16x32_bf16(ha, bw, z, 0, 0, 0);
  }

  const long ebase = e0 + wave * 16;
#pragma unroll
  for (int nt = 0; nt < 8; ++nt) {
    float bb = b2[nt * 16 + l15];
#pragma unroll
    for (int r = 0; r < 4; ++r) {
      long e = ebase + lh * 4 + r;
      if (e < nE) out[e * 128 + nt * 16 + l15] = o[nt][r] + bb;
    }
  }
}

extern "C" void kernel_launch(void* const* d_in, const int* in_sizes, int n_in,
                              void* d_out, int out_size, void* d_ws,
                              size_t ws_size, hipStream_t stream) {
  const float* src = (const float*)d_in[0];
  const float* dst = (const float*)d_in[1];
  const float* ea = (const float*)d_in[2];
  // d_in[3] = u (unused), d_in[4] = batch (unused)
  const float* W1 = (const float*)d_in[5];
  const float* b1 = (const float*)d_in[6];
  const float* W2 = (const float*)d_in[7];
  const float* b2 = (const float*)d_in[8];
  float* out = (float*)d_out;

  const int nE = in_sizes[0] / 512;  // 200000

  unsigned short* wsB1 = (unsigned short*)d_ws;
  unsigned short* wsB2 = wsB1 + 40960;
  const bool use_ws =
      ws_size >= 45056 * sizeof(unsigned short) && (nE & 63) == 0;

  if (use_ws) {
    const int nblocks = nE / 64;  // 3125
    prep_w_kernel<<<176, 256, 0, stream>>>(W1, W2, wsB1, wsB2);
    edge_mlp_kernel<true><<<nblocks, 256, 0, stream>>>(
        src, dst, ea, W1, b1, W2, b2, wsB1, wsB2, out, nE);
  } else {
    const long strips = (nE + 15) / 16;
    const int nblocks = (int)((strips + 3) / 4);
    edge_mlp_kernel<false><<<nblocks, 256, 0, stream>>>(
        src, dst, ea, W1, b1, W2, b2, nullptr, nullptr, out, nE);
  }
}

// Round 9
// 249.456 us; speedup vs baseline: 1.1862x; 1.1862x over previous
//
#include <hip/hip_runtime.h>
#include <hip/hip_bf16.h>

typedef __bf16 bf16x8 __attribute__((ext_vector_type(8)));
typedef unsigned short u16x8 __attribute__((ext_vector_type(8)));
typedef float f32x4 __attribute__((ext_vector_type(4)));
typedef unsigned int u32x4 __attribute__((ext_vector_type(4)));

using gptr_t = const __attribute__((address_space(1))) unsigned int*;
using lptr_t = __attribute__((address_space(3))) unsigned int*;
#define gp(x) ((gptr_t)(const void*)(x))
#define lp(x) ((lptr_t)(void*)(x))

// counted wait + sched fence (rule #18)
#define VMW(N)                                            \
  do {                                                    \
    asm volatile("s_waitcnt vmcnt(" #N ")" ::: "memory"); \
    __builtin_amdgcn_sched_barrier(0);                    \
  } while (0)
#define MEMFENCE asm volatile("" ::: "memory")

// ---------------------------------------------------------------------------
// Prep: pack W1 [1280x32] and W2 [32x128] (f32, row-major) into bf16 MFMA
// B-fragment order for mfma_f32_16x16x32_bf16.
// (lane l, elem j) <- W[k = kt*32 + (l>>4)*8 + j][n = nt*16 + (l&15)]
// wsB1[((kt*2+nt)*64 + l)*8 + j], wsB2[((nt)*64 + l)*8 + j]
// ---------------------------------------------------------------------------
__global__ __launch_bounds__(256) void prep_w_kernel(
    const float* __restrict__ W1, const float* __restrict__ W2,
    unsigned short* __restrict__ wsB1, unsigned short* __restrict__ wsB2) {
  int tid = blockIdx.x * 256 + threadIdx.x;
  if (tid < 40960) {                      // W1 frags: 40 ktiles * 2 ntiles * 512
    int j = tid & 7, l = (tid >> 3) & 63, nt = (tid >> 9) & 1, kt = tid >> 10;
    int k = kt * 32 + ((l >> 4) << 3) + j;
    int n = nt * 16 + (l & 15);
    __bf16 v = (__bf16)W1[k * 32 + n];
    wsB1[tid] = __builtin_bit_cast(unsigned short, v);
  } else if (tid < 45056) {               // W2 frags: 8 ntiles * 512
    int t = tid - 40960;
    int j = t & 7, l = (t >> 3) & 63, nt = t >> 9;
    int k = ((l >> 4) << 3) + j;
    int n = nt * 16 + (l & 15);
    __bf16 v = (__bf16)W2[k * 128 + n];
    wsB2[t] = __builtin_bit_cast(unsigned short, v);
  }
}

__device__ __forceinline__ u32x4 make_srd(const void* p, unsigned bytes) {
  u32x4 r;
  r[0] = (unsigned)(unsigned long long)p;
  r[1] = (unsigned)(((unsigned long long)p) >> 32);
  r[2] = bytes;
  r[3] = 0x00020000u;
  return r;
}

// WLD: all 4 weight frags of chunk C (k-tiles 2C,2C+1) into pw[BUF][0..3].
// wsB1 byte offset C*4096 + {0,1024,2048,3072}; 16B/lane coalesced.
#define WLD(BUF, SOFF)                                                      \
  asm volatile("buffer_load_dwordx4 %0, %4, %5, %6 offen offset:0\n\t"      \
               "buffer_load_dwordx4 %1, %4, %5, %6 offen offset:1024\n\t"   \
               "buffer_load_dwordx4 %2, %4, %5, %6 offen offset:2048\n\t"   \
               "buffer_load_dwordx4 %3, %4, %5, %6 offen offset:3072"       \
               : "=&v"(pw[BUF][0]), "=&v"(pw[BUF][1]), "=&v"(pw[BUF][2]),   \
                 "=&v"(pw[BUF][3])                                          \
               : "v"(voffw), "s"(srdw), "s"((unsigned)(SOFF))               \
               : "memory")

// ---------------------------------------------------------------------------
// Block = 256 threads = 64 edges. 20 chunks of 64 rows x 64 cols f32 (16 KB)
// through a 3-slot LDS ring. Per chunk (T3+T4): VMW(8) certifies chunk c
// (keeps c+1's 8 ops in flight, never drains to 0); ONE raw s_barrier;
// stage(c+2) + WLD(c+2) issued early; all 4 waves consume (2 k-tiles x
// 2 MFMAs each). Weights in explicit asm slots pw[3][4] -> zero compiler
// VMEM in the loop. 32B-pair XOR swizzle (key=row&7) on source+read, LDS
// linear (rule 21). Epilogue: per-wave LDS h-transpose + GEMM2.
// ---------------------------------------------------------------------------
template <bool USE_WS>
__global__ __launch_bounds__(256) void edge_mlp_kernel(
    const float* __restrict__ src, const float* __restrict__ dst,
    const float* __restrict__ ea, const float* __restrict__ W1,
    const float* __restrict__ b1, const float* __restrict__ W2,
    const float* __restrict__ b2, const unsigned short* __restrict__ wsB1,
    const unsigned short* __restrict__ wsB2, float* __restrict__ out, int nE) {
  __shared__ alignas(16) float xb[3][64][64];  // 48 KB ring
  const int lane = threadIdx.x & 63;
  const int wave = threadIdx.x >> 6;
  const int l15 = lane & 15;
  const int lh = lane >> 4;

  // m204 bijective XCD swizzle
  const int nwg = gridDim.x;
  const int q = nwg >> 3, rmd = nwg & 7;
  const int xcd = (int)blockIdx.x & 7, idx = (int)blockIdx.x >> 3;
  const int bid =
      (xcd < rmd ? xcd * (q + 1) : rmd * (q + 1) + (xcd - rmd) * q) + idx;

  const long e0 = (long)bid * 64;
  if (e0 >= nE) return;

  const float bias0 = b1[l15];
  const float bias1 = b1[16 + l15];

  f32x4 acc0 = {0.f, 0.f, 0.f, 0.f};
  f32x4 acc1 = {0.f, 0.f, 0.f, 0.f};

  if constexpr (USE_WS) {
    const u32x4 srdw = make_srd(wsB1, 81920u);
    const unsigned voffw = (unsigned)lane * 16u;
    u16x8 pw[3][4];

    // ---- stage chunk c into ring slot s (4 instr/wave; 4x256B runs each;
    // source XOR-swizzled per 32B pair, LDS dest linear) ----
    auto stage = [&](int c, int s) {
#pragma unroll
      for (int r = 0; r < 4; ++r) {
        const int row_l = r * 16 + wave * 4 + lh;  // chunk-local row 0..63
        const int g = ((((l15 >> 1) ^ (row_l & 7)) << 1) | (l15 & 1));
        const float* p;
        if (c < 8)
          p = src + (e0 + row_l) * 512 + c * 64 + g * 4;
        else if (c < 16)
          p = dst + (e0 + row_l) * 512 + (c - 8) * 64 + g * 4;
        else
          p = ea + (e0 + row_l) * 256 + (c - 16) * 64 + g * 4;
        __builtin_amdgcn_global_load_lds(
            gp(p), lp(&xb[s][r * 16 + wave * 4][0]), 16, 0, 0);
      }
    };

    // ---- consume chunk c from slot s, weights pw[c%3] (all waves) ----
    auto consume = [&](int c, int s) {
      const int lr = wave * 16 + l15;  // this lane's LDS row
#pragma unroll
      for (int kk = 0; kk < 2; ++kk) {
        const int pp = (kk * 4 + lh) ^ (lr & 7);  // stored 32B pair
        const f32x4* ap =
            (const f32x4*)((const char*)&xb[s][lr][0] + pp * 32);
        f32x4 lo = ap[0], hi = ap[1];
        bf16x8 a;
        a[0] = (__bf16)lo[0]; a[1] = (__bf16)lo[1];
        a[2] = (__bf16)lo[2]; a[3] = (__bf16)lo[3];
        a[4] = (__bf16)hi[0]; a[5] = (__bf16)hi[1];
        a[6] = (__bf16)hi[2]; a[7] = (__bf16)hi[3];
        acc0 = __builtin_amdgcn_mfma_f32_16x16x32_bf16(
            a, __builtin_bit_cast(bf16x8, pw[c % 3][kk * 2 + 0]), acc0, 0, 0, 0);
        acc1 = __builtin_amdgcn_mfma_f32_16x16x32_bf16(
            a, __builtin_bit_cast(bf16x8, pw[c % 3][kk * 2 + 1]), acc1, 0, 0, 0);
      }
    };

    // Prologue: chunks 0,1 -> 16 vmem ops in flight
    stage(0, 0); WLD(0, 0);
    stage(1, 1); WLD(1, 4096);

#pragma unroll
    for (int c = 0; c < 20; ++c) {
      if (c < 19) { VMW(8); } else { VMW(0); }  // certify chunk c; keep c+1
      __builtin_amdgcn_s_barrier();             // all waves' rows of c ready
      __builtin_amdgcn_sched_barrier(0);
      MEMFENCE;
      if (c + 2 < 20) {                         // issue-early next stage
        stage(c + 2, (c + 2) % 3);
        switch ((c + 2) % 3) {                  // compile-time under unroll
          case 0: WLD(0, (c + 2) * 4096); break;
          case 1: WLD(1, (c + 2) * 4096); break;
          default: WLD(2, (c + 2) * 4096); break;
        }
      }
      consume(c, c % 3);
      MEMFENCE;
    }
  } else {
    // correctness fallback (no workspace / nE not multiple of 64)
    long rowf = e0 + wave * 16 + l15;
    if (rowf >= nE) rowf = nE - 1;
    for (int t = 0; t < 40; ++t) {
      const float* p = (t < 16) ? (src + rowf * 512 + t * 32 + lh * 8)
                     : (t < 32) ? (dst + rowf * 512 + (t - 16) * 32 + lh * 8)
                                : (ea + rowf * 256 + (t - 32) * 32 + lh * 8);
      f32x4 lo = *(const f32x4*)p;
      f32x4 hi = *(const f32x4*)(p + 4);
      bf16x8 a, bf0, bf1;
      a[0] = (__bf16)lo[0]; a[1] = (__bf16)lo[1];
      a[2] = (__bf16)lo[2]; a[3] = (__bf16)lo[3];
      a[4] = (__bf16)hi[0]; a[5] = (__bf16)hi[1];
      a[6] = (__bf16)hi[2]; a[7] = (__bf16)hi[3];
#pragma unroll
      for (int j = 0; j < 8; ++j) {
        int k = t * 32 + lh * 8 + j;
        bf0[j] = (__bf16)W1[k * 32 + l15];
        bf1[j] = (__bf16)W1[k * 32 + 16 + l15];
      }
      acc0 = __builtin_amdgcn_mfma_f32_16x16x32_bf16(a, bf0, acc0, 0, 0, 0);
      acc1 = __builtin_amdgcn_mfma_f32_16x16x32_bf16(a, bf1, acc1, 0, 0, 0);
    }
  }

  // ---- bias + ELU; per-wave h-transpose in private 4KB of slot 0
  // (slot 0 last consumed at c=18; consume(19) reads slot 1 -> disjoint).
  unsigned short* hl = ((unsigned short*)&xb[0][0][0]) + wave * 2048;
#pragma unroll
  for (int r = 0; r < 4; ++r) {
    int hrow = lh * 4 + r;  // C/D layout: row=(lane>>4)*4+reg, col=lane&15
    float h0 = acc0[r] + bias0;
    float h1 = acc1[r] + bias1;
    h0 = h0 > 0.f ? h0 : (__expf(h0) - 1.f);
    h1 = h1 > 0.f ? h1 : (__expf(h1) - 1.f);
    __bf16 v0 = (__bf16)h0, v1 = (__bf16)h1;
    hl[hrow * 40 + l15] = __builtin_bit_cast(unsigned short, v0);
    hl[hrow * 40 + 16 + l15] = __builtin_bit_cast(unsigned short, v1);
  }
  asm volatile("s_waitcnt lgkmcnt(0)" ::: "memory");
  __builtin_amdgcn_sched_barrier(0);
  bf16x8 ha =
      __builtin_bit_cast(bf16x8, *(const u16x8*)(hl + l15 * 40 + lh * 8));

  // ---- GEMM2: out tiles over 8 ntiles of 16 cols ----
  f32x4 o[8];
#pragma unroll
  for (int nt = 0; nt < 8; ++nt) {
    bf16x8 bw;
    if (USE_WS) {
      bw = __builtin_bit_cast(bf16x8,
                              *(const u16x8*)(wsB2 + nt * 512 + lane * 8));
    } else {
#pragma unroll
      for (int j = 0; j < 8; ++j)
        bw[j] = (__bf16)W2[(lh * 8 + j) * 128 + nt * 16 + l15];
    }
    f32x4 z = {0.f, 0.f, 0.f, 0.f};
    o[nt] = __builtin_amdgcn_mfma_f32_16x16x32_bf16(ha, bw, z, 0, 0, 0);
  }

  const long ebase = e0 + wave * 16;
#pragma unroll
  for (int nt = 0; nt < 8; ++nt) {
    float bb = b2[nt * 16 + l15];
#pragma unroll
    for (int r = 0; r < 4; ++r) {
      long e = ebase + lh * 4 + r;
      if (e < nE) out[e * 128 + nt * 16 + l15] = o[nt][r] + bb;
    }
  }
}

extern "C" void kernel_launch(void* const* d_in, const int* in_sizes, int n_in,
                              void* d_out, int out_size, void* d_ws,
                              size_t ws_size, hipStream_t stream) {
  const float* src = (const float*)d_in[0];
  const float* dst = (const float*)d_in[1];
  const float* ea = (const float*)d_in[2];
  // d_in[3] = u (unused), d_in[4] = batch (unused)
  const float* W1 = (const float*)d_in[5];
  const float* b1 = (const float*)d_in[6];
  const float* W2 = (const float*)d_in[7];
  const float* b2 = (const float*)d_in[8];
  float* out = (float*)d_out;

  const int nE = in_sizes[0] / 512;  // 200000

  unsigned short* wsB1 = (unsigned short*)d_ws;
  unsigned short* wsB2 = wsB1 + 40960;
  const bool use_ws =
      ws_size >= 45056 * sizeof(unsigned short) && (nE & 63) == 0;

  if (use_ws) {
    const int nblocks = nE / 64;  // 3125
    prep_w_kernel<<<176, 256, 0, stream>>>(W1, W2, wsB1, wsB2);
    edge_mlp_kernel<true><<<nblocks, 256, 0, stream>>>(
        src, dst, ea, W1, b1, W2, b2, wsB1, wsB2, out, nE);
  } else {
    const long strips = (nE + 15) / 16;
    const int nblocks = (int)((strips + 3) / 4);
    edge_mlp_kernel<false><<<nblocks, 256, 0, stream>>>(
        src, dst, ea, W1, b1, W2, b2, nullptr, nullptr, out, nE);
  }
}